// Round 3
// baseline (189.106 us; speedup 1.0000x reference)
//
#include <hip/hip_runtime.h>
#include <hip/hip_bf16.h>
#include <math.h>

#define B_  2
#define S_  2048
#define H_  16
#define D_  1024
#define DK_ 64

typedef __attribute__((ext_vector_type(8))) short bf16x8;   // 8 bf16 = 4 VGPRs
typedef __attribute__((ext_vector_type(8))) unsigned short ushort8v;
typedef __attribute__((ext_vector_type(4))) float f32x4;

__device__ __forceinline__ unsigned short f2bf(float f) {
  unsigned u = __float_as_uint(f);
  unsigned r = (u + 0x7FFFu + ((u >> 16) & 1u)) >> 16;   // RNE
  return (unsigned short)r;
}
// truncation pack: two fp32 -> packed bf16x2 (P>=0; relative err ~2^-8, OK)
__device__ __forceinline__ unsigned pack_trunc(float lo, float hi) {
  return (__float_as_uint(lo) >> 16) | (__float_as_uint(hi) & 0xffff0000u);
}
__device__ __forceinline__ float fast_exp2(float x) {
#if __has_builtin(__builtin_amdgcn_exp2f)
  return __builtin_amdgcn_exp2f(x);
#else
  return __expf(x * 0.69314718056f);
#endif
}
// async global->LDS, 16B/lane. LDS dest = wave-uniform base + lane*16.
__device__ __forceinline__ void gload_lds16(const unsigned short* g,
                                            unsigned short* l) {
  __builtin_amdgcn_global_load_lds(
      (const __attribute__((address_space(1))) unsigned int*)(const void*)g,
      (__attribute__((address_space(3))) unsigned int*)(void*)l, 16, 0, 0);
}

// ---------------------------------------------------------------------------
// Cast fp32 -> bf16 for x (2048 blocks) + 4 weights (512 blocks each), plus
// 64 blocks building the RoPE cos/sin table:
//   tab[bs*32 + i] = float2(cos(tp[bs]*f_i), sin(tp[bs]*f_i)),
//   f_i = 10000^(-2i/64) = exp2f(-0.4152410118*i)  (bitwise-identical to the
//   expressions previously evaluated in the gemm_qkv epilogue).
// ---------------------------------------------------------------------------
__global__ __launch_bounds__(256)
void cast5_bf16(const float* __restrict__ x,  const float* __restrict__ wq,
                const float* __restrict__ wk, const float* __restrict__ wv,
                const float* __restrict__ wo,
                unsigned short* __restrict__ xb,  unsigned short* __restrict__ wqb,
                unsigned short* __restrict__ wkb, unsigned short* __restrict__ wvb,
                unsigned short* __restrict__ wob,
                const int* __restrict__ tp, float* __restrict__ tab)
{
  const int idx = blockIdx.x;
  if (idx >= 4096) {
    // RoPE table: 64 blocks x 256 threads x 8 entries = 131072 = B*S*32
    const int e0 = ((idx - 4096) * 256 + threadIdx.x) * 8;
    const int bs = e0 >> 5;              // fixed for all 8 entries
    const int i0 = e0 & 31;
    const float p = (float)tp[bs];
    #pragma unroll
    for (int j = 0; j < 8; ++j) {
      const int i = i0 + j;
      const float freq = exp2f(-0.4152410118f * (float)i);
      const float ang  = p * freq;
      float2 cs;
      cs.x = __cosf(ang);
      cs.y = __sinf(ang);
      *(float2*)&tab[2 * (e0 + j)] = cs;
    }
    return;
  }
  const float* s; unsigned short* d; int lblk;
  if (idx < 2048) { s = x; d = xb; lblk = idx; }
  else {
    int t = idx - 2048;
    int w = t >> 9;          // 0..3
    lblk  = t & 511;
    s = (w == 0) ? wq  : (w == 1) ? wk  : (w == 2) ? wv  : wo;
    d = (w == 0) ? wqb : (w == 1) ? wkb : (w == 2) ? wvb : wob;
  }
  size_t i0 = ((size_t)lblk * 256 + threadIdx.x) * 8;
  float4 v0 = *(const float4*)(s + i0);
  float4 v1 = *(const float4*)(s + i0 + 4);
  ushort8v o;
  o[0] = f2bf(v0.x); o[1] = f2bf(v0.y); o[2] = f2bf(v0.z); o[3] = f2bf(v0.w);
  o[4] = f2bf(v1.x); o[5] = f2bf(v1.y); o[6] = f2bf(v1.z); o[7] = f2bf(v1.w);
  *(ushort8v*)(d + i0) = o;
}

// ---------------------------------------------------------------------------
// Fused QKV projection GEMM, 128x128 tile, BK=64. Mod-8 XOR-swizzled LDS rows.
// blockIdx.z: 0=Q, 1=K, 2=V (operand swap -> V^T). XCD-swizzled block map.
// RoPE epilogue now reads the precomputed cos/sin table (no transcendentals).
// ---------------------------------------------------------------------------
__global__ __launch_bounds__(256)
void gemm_qkv(const unsigned short* __restrict__ A0,
              const unsigned short* __restrict__ W0,
              const unsigned short* __restrict__ W1,
              const unsigned short* __restrict__ W2,
              unsigned short* __restrict__ qh,
              unsigned short* __restrict__ kh,
              unsigned short* __restrict__ vt,
              const float* __restrict__ tab)
{
  const int z = blockIdx.z;

  // bijective XCD remap of (x,y): f 8 bits = [by_hi:2][bx:3][by_lo:3]
  const int f  = blockIdx.x + (blockIdx.y << 3);
  const int bx = (f >> 3) & 7;
  const int by = (f & 7) | ((f >> 6) << 3);

  __shared__ unsigned short As[128 * 64];   // 16 KB
  __shared__ unsigned short Bs[128 * 64];   // 16 KB

  const int tid   = threadIdx.x;
  const int wave  = tid >> 6;
  const int lane  = tid & 63;
  const int quad  = lane >> 4;
  const int col16 = lane & 15;
  const int wr    = (wave >> 1) * 64;
  const int wc    = (wave & 1) * 64;

  const int row0 = (z == 2) ? bx * 128 : by * 128;
  const int col0 = (z == 2) ? by * 128 : bx * 128;
  const unsigned short* Aptr = (z == 2) ? W2 : A0;
  const unsigned short* Bptr = (z == 0) ? W0 : (z == 1) ? W1 : A0;

  const int srow = wave * 8 + (lane >> 3);
  const int scol = ((lane & 7) ^ ((lane >> 3) & 7)) * 8;
  const unsigned short* gA = Aptr + (size_t)(row0 + srow) * D_ + scol;
  const unsigned short* gB = Bptr + (size_t)(col0 + srow) * D_ + scol;

  f32x4 acc[4][4];
  #pragma unroll
  for (int mt = 0; mt < 4; ++mt)
    #pragma unroll
    for (int nt = 0; nt < 4; ++nt)
      #pragma unroll
      for (int r = 0; r < 4; ++r) acc[mt][nt][r] = 0.f;

  for (int k0 = 0; k0 < D_; k0 += 64) {
    __syncthreads();
    #pragma unroll
    for (int p = 0; p < 4; ++p) {
      gload_lds16(gA + (size_t)(p * 32) * D_ + k0, &As[(p * 32 + wave * 8) * 64]);
      gload_lds16(gB + (size_t)(p * 32) * D_ + k0, &Bs[(p * 32 + wave * 8) * 64]);
    }
    __syncthreads();

    #pragma unroll
    for (int h = 0; h < 2; ++h) {
      const int jo = ((h * 4 + quad) ^ (col16 & 7)) * 8;
      bf16x8 af[4], bfr[4];
      #pragma unroll
      for (int mt = 0; mt < 4; ++mt)
        af[mt] = *(const bf16x8*)&As[(wr + mt * 16 + col16) * 64 + jo];
      #pragma unroll
      for (int nt = 0; nt < 4; ++nt)
        bfr[nt] = *(const bf16x8*)&Bs[(wc + nt * 16 + col16) * 64 + jo];

      #pragma unroll
      for (int mt = 0; mt < 4; ++mt)
        #pragma unroll
        for (int nt = 0; nt < 4; ++nt)
          acc[mt][nt] = __builtin_amdgcn_mfma_f32_16x16x32_bf16(
              af[mt], bfr[nt], acc[mt][nt], 0, 0, 0);
    }
  }

  if (z == 2) {
    #pragma unroll
    for (int mt = 0; mt < 4; ++mt)
      #pragma unroll
      for (int r = 0; r < 4; ++r) {
        int c = row0 + wr + mt * 16 + quad * 4 + r;   // channel
        int h = c >> 6, d = c & 63;
        #pragma unroll
        for (int nt = 0; nt < 4; ++nt) {
          int t  = col0 + wc + nt * 16 + col16;       // token
          int bb = t >> 11, sl = t & (S_ - 1);
          vt[((size_t)((bb << 4) + h) * DK_ + d) * S_ + sl] =
              f2bf(acc[mt][nt][r]);
        }
      }
  } else {
    unsigned short* C = z ? kh : qh;
    const float qs = z ? 1.0f : 0.1803368801111204f;  // 0.125*log2(e) for Q
    const float sgn = (col16 & 1) ? 1.f : -1.f;
    int iofs[4];
    #pragma unroll
    for (int nt = 0; nt < 4; ++nt)
      iofs[nt] = ((wc + nt * 16 + col16) & 63) >> 1;  // freq-pair index
    #pragma unroll
    for (int mt = 0; mt < 4; ++mt)
      #pragma unroll
      for (int r = 0; r < 4; ++r) {
        int row = row0 + wr + mt * 16 + quad * 4 + r;
        const float2* trow = (const float2*)(tab + (size_t)row * 64);
        #pragma unroll
        for (int nt = 0; nt < 4; ++nt) {
          int col = col0 + wc + nt * 16 + col16;
          float2 cs = trow[iofs[nt]];
          float val = acc[mt][nt][r];
          float oth = __shfl_xor(val, 1);
          C[(size_t)row * D_ + col] = f2bf((val * cs.x + oth * sgn * cs.y) * qs);
        }
      }
  }
}

// ---------------------------------------------------------------------------
// Wo projection GEMM, 64(M)x128(N) tile, BK=64. XCD-swizzled block map.
// ---------------------------------------------------------------------------
__global__ __launch_bounds__(256)
void gemm_wo(const unsigned short* __restrict__ A,
             const unsigned short* __restrict__ W,
             float* __restrict__ C)
{
  __shared__ unsigned short As[64 * 64];    // 8 KB
  __shared__ unsigned short Bs[128 * 64];   // 16 KB

  const int f  = blockIdx.x + (blockIdx.y << 3);
  const int bx = (f >> 3) & 7;
  const int by = (f & 7) | ((f >> 6) << 3);

  const int tid   = threadIdx.x;
  const int wave  = tid >> 6;
  const int lane  = tid & 63;
  const int quad  = lane >> 4;
  const int col16 = lane & 15;
  const int row0  = by * 64;
  const int col0  = bx * 128;
  const int wr    = (wave >> 1) * 32;
  const int wc    = (wave & 1) * 64;

  const int srow = wave * 8 + (lane >> 3);
  const int scol = ((lane & 7) ^ ((lane >> 3) & 7)) * 8;
  const unsigned short* gA = A + (size_t)(row0 + srow) * D_ + scol;
  const unsigned short* gB = W + (size_t)(col0 + srow) * D_ + scol;

  f32x4 acc[2][4];
  #pragma unroll
  for (int mt = 0; mt < 2; ++mt)
    #pragma unroll
    for (int nt = 0; nt < 4; ++nt)
      #pragma unroll
      for (int r = 0; r < 4; ++r) acc[mt][nt][r] = 0.f;

  for (int k0 = 0; k0 < D_; k0 += 64) {
    __syncthreads();
    #pragma unroll
    for (int p = 0; p < 2; ++p)
      gload_lds16(gA + (size_t)(p * 32) * D_ + k0, &As[(p * 32 + wave * 8) * 64]);
    #pragma unroll
    for (int p = 0; p < 4; ++p)
      gload_lds16(gB + (size_t)(p * 32) * D_ + k0, &Bs[(p * 32 + wave * 8) * 64]);
    __syncthreads();

    #pragma unroll
    for (int h = 0; h < 2; ++h) {
      const int jo = ((h * 4 + quad) ^ (col16 & 7)) * 8;
      bf16x8 af[2], bfr[4];
      #pragma unroll
      for (int mt = 0; mt < 2; ++mt)
        af[mt] = *(const bf16x8*)&As[(wr + mt * 16 + col16) * 64 + jo];
      #pragma unroll
      for (int nt = 0; nt < 4; ++nt)
        bfr[nt] = *(const bf16x8*)&Bs[(wc + nt * 16 + col16) * 64 + jo];

      #pragma unroll
      for (int mt = 0; mt < 2; ++mt)
        #pragma unroll
        for (int nt = 0; nt < 4; ++nt)
          acc[mt][nt] = __builtin_amdgcn_mfma_f32_16x16x32_bf16(
              af[mt], bfr[nt], acc[mt][nt], 0, 0, 0);
    }
  }

  #pragma unroll
  for (int mt = 0; mt < 2; ++mt)
    #pragma unroll
    for (int r = 0; r < 4; ++r) {
      int row = row0 + wr + mt * 16 + quad * 4 + r;
      #pragma unroll
      for (int nt = 0; nt < 4; ++nt) {
        int col = col0 + wc + nt * 16 + col16;
        C[(size_t)row * D_ + col] = acc[mt][nt][r];
      }
    }
}

// ---------------------------------------------------------------------------
// Flash attention, 8-wave key-parity structure (unchanged from R2):
//   1 q-tile (64 rows) per block, 512 threads: wave w -> row-group rw = w&3,
//   key-parity p = w>>2 (halves g ≡ p mod 2). Fixed-max softmax -> parity
//   partials combine by pure addition. Rolling K/V slots, counted vmcnt(2).
// ---------------------------------------------------------------------------
__global__ __launch_bounds__(512, 6)
void attn_mfma(const unsigned short* __restrict__ Q,
               const unsigned short* __restrict__ K,
               const unsigned short* __restrict__ Vt,
               unsigned short* __restrict__ O)
{
  const int f   = blockIdx.x;          // 0..1023
  const int qt  = 31 - (f >> 5);       // big q-tiles dispatched first
  const int bh  = f & 31;              // xcd = f&7 ~ bh&7 -> L2 locality
  const int b   = bh >> 4, h = bh & 15;

  const int tid  = threadIdx.x;
  const int w    = tid >> 6;
  const int lane = tid & 63;
  const int quad = lane >> 4;
  const int col  = lane & 15;
  const int rw   = w & 3;              // row-wave 0..3
  const int p    = w >> 2;             // key-parity group 0/1
  const int qlocal = rw * 16 + col;

  __shared__ unsigned short Ks[2 * 4096];               // 2 x 64-key slot, 16 KB
  __shared__ unsigned short Vs[2 * 4096];               // 16 KB
  __shared__ __align__(16) unsigned short Pl[8][16][72]; // 18 KB, per-wave P

  const size_t qkbase = (size_t)b * S_ * D_ + (size_t)h * DK_;
  const size_t vtbase = (size_t)bh * DK_ * S_;

  const int qrow = qt * 64 + qlocal;
  bf16x8 qf[2];
  qf[0] = *(const bf16x8*)(Q + qkbase + (size_t)qrow * D_ + quad * 8);
  qf[1] = *(const bf16x8*)(Q + qkbase + (size_t)qrow * D_ + 32 + quad * 8);

  // staging: wave covers 16 rows (2 gloads x 8 rows) of its own slot p.
  const int lr8 = lane >> 3;                       // 0..7 row within 8
  const int sj  = ((lane & 7) ^ (lr8 & 7)) * 8;    // swizzled source octet

  auto stageK = [&](int g) {
    const int gc = (g > qt) ? qt : g;
    const unsigned short* s =
        K + qkbase + (size_t)(gc * 64 + rw * 16 + lr8) * D_ + sj;
    #pragma unroll
    for (int pp = 0; pp < 2; ++pp)
      gload_lds16(s + (size_t)(pp * 8) * D_, &Ks[p * 4096 + (rw * 16 + pp * 8) * 64]);
  };
  auto stageV = [&](int g) {
    const int gc = (g > qt) ? qt : g;
    const unsigned short* s =
        Vt + vtbase + (size_t)(rw * 16 + lr8) * S_ + gc * 64 + sj;
    #pragma unroll
    for (int pp = 0; pp < 2; ++pp)
      gload_lds16(s + (size_t)(pp * 8) * S_, &Vs[p * 4096 + (rw * 16 + pp * 8) * 64]);
  };

  f32x4 Oacc[4];
  #pragma unroll
  for (int nb = 0; nb < 4; ++nb)
    #pragma unroll
    for (int r = 0; r < 4; ++r) Oacc[nb][r] = 0.f;
  float l_i = 0.f;

  const int M  = (qt >> 1) + 1;        // pair-iterations
  const int jx = quad ^ (col & 7);
  const unsigned short* KsH = Ks + p * 4096;
  const unsigned short* VsH = Vs + p * 4096;
  unsigned short (*Plw)[72] = Pl[w];

  stageK(p);
  stageV(p);
  asm volatile("s_waitcnt vmcnt(0)" ::: "memory");
  __builtin_amdgcn_s_barrier();
  __builtin_amdgcn_sched_barrier(0);

  for (int m = 0; m < M; ++m) {
    const int g    = 2 * m + p;
    const bool act = (g <= qt);
    const bool dg  = (g == qt);

    f32x4 st[4];
    if (act) {                       // QK^T from own K slot
      __builtin_amdgcn_s_setprio(1);
      #pragma unroll
      for (int nb = 0; nb < 4; ++nb) {
        const int s0 = (nb * 16 + col) * 8 + jx;
        bf16x8 ka0 = *(const bf16x8*)(KsH + s0 * 8);
        bf16x8 ka1 = *(const bf16x8*)(KsH + (s0 ^ 4) * 8);
        f32x4 a = {-24.f, -24.f, -24.f, -24.f};   // fixed-max bias
        a = __builtin_amdgcn_mfma_f32_16x16x32_bf16(ka0, qf[0], a, 0, 0, 0);
        a = __builtin_amdgcn_mfma_f32_16x16x32_bf16(ka1, qf[1], a, 0, 0, 0);
        st[nb] = a;
      }
      __builtin_amdgcn_s_setprio(0);
    }
    __builtin_amdgcn_sched_barrier(0);
    __builtin_amdgcn_s_barrier();            // all QK K-reads complete
    __builtin_amdgcn_sched_barrier(0);

    stageK(2 * m + 2 + p);                   // overwrite own K slot (next pair)

    if (act) {                               // softmax (fixed-max, exp2 domain)
      if (dg) {
        #pragma unroll
        for (int nb = 0; nb < 4; ++nb)
          #pragma unroll
          for (int r = 0; r < 4; ++r)
            if (nb * 16 + quad * 4 + r > qlocal) st[nb][r] = -1e30f;
      }
      float rsum = 0.f;
      #pragma unroll
      for (int nb = 0; nb < 4; ++nb)
        #pragma unroll
        for (int r = 0; r < 4; ++r) {
          float pv = fast_exp2(st[nb][r]);
          st[nb][r] = pv;
          rsum += pv;
        }
      rsum += __shfl_xor(rsum, 16);
      rsum += __shfl_xor(rsum, 32);
      l_i += rsum;
      #pragma unroll
      for (int nb = 0; nb < 4; ++nb) {
        uint2 pk;
        pk.x = pack_trunc(st[nb][0], st[nb][1]);
        pk.y = pack_trunc(st[nb][2], st[nb][3]);
        *(uint2*)&Plw[col][nb * 16 + quad * 4] = pk;
      }
    }

    asm volatile("s_waitcnt vmcnt(2)" ::: "memory");  // own V(pair m) landed
    __builtin_amdgcn_sched_barrier(0);
    __builtin_amdgcn_s_barrier();            // everyone's V landed
    __builtin_amdgcn_sched_barrier(0);

    if (act) {                               // PV from own V slot
      bf16x8 pf0 = *(const bf16x8*)&Plw[col][quad * 8];
      bf16x8 pf1 = *(const bf16x8*)&Plw[col][32 + quad * 8];
      __builtin_amdgcn_s_setprio(1);
      #pragma unroll
      for (int nb = 0; nb < 4; ++nb) {
        const int s0 = (nb * 16 + col) * 8 + jx;
        bf16x8 va0 = *(const bf16x8*)(VsH + s0 * 8);
        bf16x8 va1 = *(const bf16x8*)(VsH + (s0 ^ 4) * 8);
        Oacc[nb] = __builtin_amdgcn_mfma_f32_16x16x32_bf16(va0, pf0, Oacc[nb], 0, 0, 0);
        Oacc[nb] = __builtin_amdgcn_mfma_f32_16x16x32_bf16(va1, pf1, Oacc[nb], 0, 0, 0);
      }
      __builtin_amdgcn_s_setprio(0);
    }
    __builtin_amdgcn_sched_barrier(0);
    __builtin_amdgcn_s_barrier();            // all V-reads complete
    __builtin_amdgcn_sched_barrier(0);

    stageV(2 * m + 2 + p);                   // overwrite own V slot (next pair)
    asm volatile("s_waitcnt vmcnt(2)" ::: "memory");  // own K(next) landed
    __builtin_amdgcn_sched_barrier(0);
    __builtin_amdgcn_s_barrier();            // everyone's K landed
    __builtin_amdgcn_sched_barrier(0);
  }

  // ---- combine parity partials (pure add: fixed-max, no rescale) ----
  asm volatile("s_waitcnt vmcnt(0)" ::: "memory");    // tail DMA landed
  __syncthreads();                                    // LDS reusable
  float* sc = (float*)&Pl[0][0][0];                   // 18 KB scratch
  if (p == 1) {
    float* d0 = sc + ((size_t)(rw * 64 + lane)) * 18;
    #pragma unroll
    for (int nb = 0; nb < 4; ++nb)
      #pragma unroll
      for (int r = 0; r < 4; ++r) d0[nb * 4 + r] = Oacc[nb][r];
    d0[16] = l_i;
  }
  __syncthreads();
  if (p == 0) {
    const float* s0 = sc + ((size_t)(rw * 64 + lane)) * 18;
    const float inv = 1.0f / (l_i + s0[16]);
    #pragma unroll
    for (int nb = 0; nb < 4; ++nb) {
      int d = nb * 16 + quad * 4;
      ushort4 oa;
      oa.x = f2bf((Oacc[nb][0] + s0[nb * 4 + 0]) * inv);
      oa.y = f2bf((Oacc[nb][1] + s0[nb * 4 + 1]) * inv);
      oa.z = f2bf((Oacc[nb][2] + s0[nb * 4 + 2]) * inv);
      oa.w = f2bf((Oacc[nb][3] + s0[nb * 4 + 3]) * inv);
      *(ushort4*)(O + (size_t)b * S_ * D_ + (size_t)qrow * D_ + h * DK_ + d) = oa;
    }
  }
}

// ---------------------------------------------------------------------------
extern "C" void kernel_launch(void* const* d_in, const int* in_sizes, int n_in,
                              void* d_out, int out_size, void* d_ws, size_t ws_size,
                              hipStream_t stream)
{
  const float* x  = (const float*)d_in[0];
  const float* Wq = (const float*)d_in[1];
  const float* Wk = (const float*)d_in[2];
  const float* Wv = (const float*)d_in[3];
  const float* Wo = (const float*)d_in[4];
  const int*   tp = (const int*)d_in[5];
  float* out = (float*)d_out;

  const size_t NTOK = (size_t)B_ * S_ * D_;     // 4,194,304 elements
  const size_t NW   = (size_t)D_ * D_;          // 1,048,576
  unsigned short* qh  = (unsigned short*)d_ws;  // bf16 [B,S,D]
  unsigned short* kh  = qh + NTOK;
  unsigned short* vt  = kh + NTOK;              // bf16 [B*H, 64, S]
  unsigned short* xb  = vt + NTOK;              // bf16 [B,S,D]; reused as ab
  unsigned short* wqb = xb + NTOK;
  unsigned short* wkb = wqb + NW;
  unsigned short* wvb = wkb + NW;
  unsigned short* wob = wvb + NW;
  float*          tab = (float*)(wob + NW);     // [B*S, 32] float2 = 1 MB
  unsigned short* ab  = xb;                     // alias: xb dead after QKV gemm

  // fp32 -> bf16 casts + RoPE cos/sin table build
  cast5_bf16<<<dim3(4096 + 64), 256, 0, stream>>>(
      x, Wq, Wk, Wv, Wo, xb, wqb, wkb, wvb, wob, tp, tab);

  // fused QKV projection + table-RoPE + Q-scale + direct-V^T, BK=64
  gemm_qkv<<<dim3(D_ / 128, (B_ * S_) / 128, 3), 256, 0, stream>>>(
      xb, wqb, wkb, wvb, qh, kh, vt, tab);

  // 8-wave key-parity flash attention (fixed-max softmax) -> bf16 ab
  attn_mfma<<<dim3(32 * 32), 512, 0, stream>>>(qh, kh, vt, ab);

  // output projection, 64x128 tiles, BK=64 -> fp32 out
  gemm_wo<<<dim3(D_ / 128, (B_ * S_) / 64), 256, 0, stream>>>(ab, wob, out);
}

// Round 4
// 172.380 us; speedup vs baseline: 1.0970x; 1.0970x over previous
//
#include <hip/hip_runtime.h>
#include <hip/hip_bf16.h>
#include <math.h>

#define B_  2
#define S_  2048
#define H_  16
#define D_  1024
#define DK_ 64

typedef __attribute__((ext_vector_type(8))) short bf16x8;   // 8 bf16 = 4 VGPRs
typedef __attribute__((ext_vector_type(8))) unsigned short ushort8v;
typedef __attribute__((ext_vector_type(4))) float f32x4;

__device__ __forceinline__ unsigned short f2bf(float f) {
  unsigned u = __float_as_uint(f);
  unsigned r = (u + 0x7FFFu + ((u >> 16) & 1u)) >> 16;   // RNE
  return (unsigned short)r;
}
// truncation pack: two fp32 -> packed bf16x2 (P>=0; relative err ~2^-8, OK)
__device__ __forceinline__ unsigned pack_trunc(float lo, float hi) {
  return (__float_as_uint(lo) >> 16) | (__float_as_uint(hi) & 0xffff0000u);
}
__device__ __forceinline__ float fast_exp2(float x) {
#if __has_builtin(__builtin_amdgcn_exp2f)
  return __builtin_amdgcn_exp2f(x);
#else
  return __expf(x * 0.69314718056f);
#endif
}
// async global->LDS, 16B/lane. LDS dest = wave-uniform base + lane*16.
__device__ __forceinline__ void gload_lds16(const unsigned short* g,
                                            unsigned short* l) {
  __builtin_amdgcn_global_load_lds(
      (const __attribute__((address_space(1))) unsigned int*)(const void*)g,
      (__attribute__((address_space(3))) unsigned int*)(void*)l, 16, 0, 0);
}

// ---------------------------------------------------------------------------
// Cast fp32 -> bf16 for x (2048 blocks) + 4 weights (512 blocks each).
// ---------------------------------------------------------------------------
__global__ __launch_bounds__(256)
void cast5_bf16(const float* __restrict__ x,  const float* __restrict__ wq,
                const float* __restrict__ wk, const float* __restrict__ wv,
                const float* __restrict__ wo,
                unsigned short* __restrict__ xb,  unsigned short* __restrict__ wqb,
                unsigned short* __restrict__ wkb, unsigned short* __restrict__ wvb,
                unsigned short* __restrict__ wob)
{
  const int idx = blockIdx.x;
  const float* s; unsigned short* d; int lblk;
  if (idx < 2048) { s = x; d = xb; lblk = idx; }
  else {
    int t = idx - 2048;
    int w = t >> 9;          // 0..3
    lblk  = t & 511;
    s = (w == 0) ? wq  : (w == 1) ? wk  : (w == 2) ? wv  : wo;
    d = (w == 0) ? wqb : (w == 1) ? wkb : (w == 2) ? wvb : wob;
  }
  size_t i0 = ((size_t)lblk * 256 + threadIdx.x) * 8;
  float4 v0 = *(const float4*)(s + i0);
  float4 v1 = *(const float4*)(s + i0 + 4);
  ushort8v o;
  o[0] = f2bf(v0.x); o[1] = f2bf(v0.y); o[2] = f2bf(v0.z); o[3] = f2bf(v0.w);
  o[4] = f2bf(v1.x); o[5] = f2bf(v1.y); o[6] = f2bf(v1.z); o[7] = f2bf(v1.w);
  *(ushort8v*)(d + i0) = o;
}

// ---------------------------------------------------------------------------
// Fused QKV projection GEMM, 128x128 tile, BK=64. Mod-8 XOR-swizzled LDS rows.
// blockIdx.z: 0=Q, 1=K, 2=V (operand swap -> V^T). XCD-swizzled block map.
// NEW (R4): rolling double-buffered LDS with counted vmcnt(8) — stage K-tile
// k+1 into buf[(k+1)&1] before computing buf[k&1]; raw s_barriers, no
// mid-loop vmcnt(0) drain (T3/T4 minimal 2-phase, proven in attn R2).
// RoPE epilogue: inline __sinf/__cosf on fp32 accs (R2 version — the R3
// table variant regressed 45.8->60.5 us via serial L2-latency chain).
// ---------------------------------------------------------------------------
__global__ __launch_bounds__(256)
void gemm_qkv(const unsigned short* __restrict__ A0,
              const unsigned short* __restrict__ W0,
              const unsigned short* __restrict__ W1,
              const unsigned short* __restrict__ W2,
              unsigned short* __restrict__ qh,
              unsigned short* __restrict__ kh,
              unsigned short* __restrict__ vt,
              const int* __restrict__ tp)
{
  const int z = blockIdx.z;

  // bijective XCD remap of (x,y): f 8 bits = [by_hi:2][bx:3][by_lo:3]
  const int f  = blockIdx.x + (blockIdx.y << 3);
  const int bx = (f >> 3) & 7;
  const int by = (f & 7) | ((f >> 6) << 3);

  __shared__ unsigned short As[2][128 * 64];   // 32 KB (double-buffered)
  __shared__ unsigned short Bs[2][128 * 64];   // 32 KB
  __shared__ int tps[128];

  const int tid   = threadIdx.x;
  const int wave  = tid >> 6;
  const int lane  = tid & 63;
  const int quad  = lane >> 4;
  const int col16 = lane & 15;
  const int wr    = (wave >> 1) * 64;
  const int wc    = (wave & 1) * 64;

  const int row0 = (z == 2) ? bx * 128 : by * 128;
  const int col0 = (z == 2) ? by * 128 : bx * 128;
  const unsigned short* Aptr = (z == 2) ? W2 : A0;
  const unsigned short* Bptr = (z == 0) ? W0 : (z == 1) ? W1 : A0;

  if (z < 2 && tid < 128) tps[tid] = tp[row0 + tid];

  const int srow = wave * 8 + (lane >> 3);
  const int scol = ((lane & 7) ^ ((lane >> 3) & 7)) * 8;
  const unsigned short* gA = Aptr + (size_t)(row0 + srow) * D_ + scol;
  const unsigned short* gB = Bptr + (size_t)(col0 + srow) * D_ + scol;

  f32x4 acc[4][4];
  #pragma unroll
  for (int mt = 0; mt < 4; ++mt)
    #pragma unroll
    for (int nt = 0; nt < 4; ++nt)
      #pragma unroll
      for (int r = 0; r < 4; ++r) acc[mt][nt][r] = 0.f;

  // stage K-tile k (8 gload_lds/wave) into buffer k&1
  auto stage = [&](int k) {
    const int k0 = k << 6;
    unsigned short* Ad = &As[k & 1][wave * 8 * 64];
    unsigned short* Bd = &Bs[k & 1][wave * 8 * 64];
    #pragma unroll
    for (int p = 0; p < 4; ++p) {
      gload_lds16(gA + (size_t)(p * 32) * D_ + k0, Ad + (p * 32) * 64);
      gload_lds16(gB + (size_t)(p * 32) * D_ + k0, Bd + (p * 32) * 64);
    }
  };

  stage(0);
  for (int k = 0; k < 16; ++k) {
    if (k < 15) {
      stage(k + 1);                                    // prefetch next tile
      asm volatile("s_waitcnt vmcnt(8)" ::: "memory"); // tile k landed (ours)
    } else {
      asm volatile("s_waitcnt vmcnt(0)" ::: "memory");
    }
    __builtin_amdgcn_sched_barrier(0);
    __builtin_amdgcn_s_barrier();                      // tile k landed (all)
    __builtin_amdgcn_sched_barrier(0);

    const unsigned short* Ac = &As[k & 1][0];
    const unsigned short* Bc = &Bs[k & 1][0];
    #pragma unroll
    for (int h = 0; h < 2; ++h) {
      const int jo = ((h * 4 + quad) ^ (col16 & 7)) * 8;
      bf16x8 af[4], bfr[4];
      #pragma unroll
      for (int mt = 0; mt < 4; ++mt)
        af[mt] = *(const bf16x8*)&Ac[(wr + mt * 16 + col16) * 64 + jo];
      #pragma unroll
      for (int nt = 0; nt < 4; ++nt)
        bfr[nt] = *(const bf16x8*)&Bc[(wc + nt * 16 + col16) * 64 + jo];

      #pragma unroll
      for (int mt = 0; mt < 4; ++mt)
        #pragma unroll
        for (int nt = 0; nt < 4; ++nt)
          acc[mt][nt] = __builtin_amdgcn_mfma_f32_16x16x32_bf16(
              af[mt], bfr[nt], acc[mt][nt], 0, 0, 0);
    }

    if (k < 15) {
      __builtin_amdgcn_sched_barrier(0);
      __builtin_amdgcn_s_barrier();   // buf[k&1] reads done -> safe to overwrite
      __builtin_amdgcn_sched_barrier(0);
    }
  }

  if (z == 2) {
    #pragma unroll
    for (int mt = 0; mt < 4; ++mt)
      #pragma unroll
      for (int r = 0; r < 4; ++r) {
        int c = row0 + wr + mt * 16 + quad * 4 + r;   // channel
        int h = c >> 6, d = c & 63;
        #pragma unroll
        for (int nt = 0; nt < 4; ++nt) {
          int t  = col0 + wc + nt * 16 + col16;       // token
          int bb = t >> 11, sl = t & (S_ - 1);
          vt[((size_t)((bb << 4) + h) * DK_ + d) * S_ + sl] =
              f2bf(acc[mt][nt][r]);
        }
      }
  } else {
    unsigned short* C = z ? kh : qh;
    const float qs = z ? 1.0f : 0.1803368801111204f;  // 0.125*log2(e) for Q
    const float sgn = (col16 & 1) ? 1.f : -1.f;
    float freqr[4];
    #pragma unroll
    for (int nt = 0; nt < 4; ++nt) {
      int i = ((wc + nt * 16 + col16) & 63) >> 1;
      freqr[nt] = exp2f(-0.4152410118f * (float)i);   // 10000^(-2i/64)
    }
    #pragma unroll
    for (int mt = 0; mt < 4; ++mt)
      #pragma unroll
      for (int r = 0; r < 4; ++r) {
        int rl  = wr + mt * 16 + quad * 4 + r;
        int row = row0 + rl;
        float p = (float)tps[rl];
        #pragma unroll
        for (int nt = 0; nt < 4; ++nt) {
          int col = col0 + wc + nt * 16 + col16;
          float ang = p * freqr[nt];
          float sn = __sinf(ang), cs = __cosf(ang);
          float val = acc[mt][nt][r];
          float oth = __shfl_xor(val, 1);
          C[(size_t)row * D_ + col] = f2bf((val * cs + oth * sgn * sn) * qs);
        }
      }
  }
}

// ---------------------------------------------------------------------------
// Wo projection GEMM, 64(M)x128(N) tile, BK=64. XCD-swizzled block map.
// NEW (R4): same rolling double-buffer + counted vmcnt(6) as gemm_qkv.
// ---------------------------------------------------------------------------
__global__ __launch_bounds__(256)
void gemm_wo(const unsigned short* __restrict__ A,
             const unsigned short* __restrict__ W,
             float* __restrict__ C)
{
  __shared__ unsigned short As[2][64 * 64];    // 16 KB
  __shared__ unsigned short Bs[2][128 * 64];   // 32 KB

  const int f  = blockIdx.x + (blockIdx.y << 3);
  const int bx = (f >> 3) & 7;
  const int by = (f & 7) | ((f >> 6) << 3);

  const int tid   = threadIdx.x;
  const int wave  = tid >> 6;
  const int lane  = tid & 63;
  const int quad  = lane >> 4;
  const int col16 = lane & 15;
  const int row0  = by * 64;
  const int col0  = bx * 128;
  const int wr    = (wave >> 1) * 32;
  const int wc    = (wave & 1) * 64;

  const int srow = wave * 8 + (lane >> 3);
  const int scol = ((lane & 7) ^ ((lane >> 3) & 7)) * 8;
  const unsigned short* gA = A + (size_t)(row0 + srow) * D_ + scol;
  const unsigned short* gB = W + (size_t)(col0 + srow) * D_ + scol;

  f32x4 acc[2][4];
  #pragma unroll
  for (int mt = 0; mt < 2; ++mt)
    #pragma unroll
    for (int nt = 0; nt < 4; ++nt)
      #pragma unroll
      for (int r = 0; r < 4; ++r) acc[mt][nt][r] = 0.f;

  auto stage = [&](int k) {
    const int k0 = k << 6;
    unsigned short* Ad = &As[k & 1][wave * 8 * 64];
    unsigned short* Bd = &Bs[k & 1][wave * 8 * 64];
    #pragma unroll
    for (int p = 0; p < 2; ++p)
      gload_lds16(gA + (size_t)(p * 32) * D_ + k0, Ad + (p * 32) * 64);
    #pragma unroll
    for (int p = 0; p < 4; ++p)
      gload_lds16(gB + (size_t)(p * 32) * D_ + k0, Bd + (p * 32) * 64);
  };

  stage(0);
  for (int k = 0; k < 16; ++k) {
    if (k < 15) {
      stage(k + 1);
      asm volatile("s_waitcnt vmcnt(6)" ::: "memory");
    } else {
      asm volatile("s_waitcnt vmcnt(0)" ::: "memory");
    }
    __builtin_amdgcn_sched_barrier(0);
    __builtin_amdgcn_s_barrier();
    __builtin_amdgcn_sched_barrier(0);

    const unsigned short* Ac = &As[k & 1][0];
    const unsigned short* Bc = &Bs[k & 1][0];
    #pragma unroll
    for (int h = 0; h < 2; ++h) {
      const int jo = ((h * 4 + quad) ^ (col16 & 7)) * 8;
      bf16x8 af[2], bfr[4];
      #pragma unroll
      for (int mt = 0; mt < 2; ++mt)
        af[mt] = *(const bf16x8*)&Ac[(wr + mt * 16 + col16) * 64 + jo];
      #pragma unroll
      for (int nt = 0; nt < 4; ++nt)
        bfr[nt] = *(const bf16x8*)&Bc[(wc + nt * 16 + col16) * 64 + jo];

      #pragma unroll
      for (int mt = 0; mt < 2; ++mt)
        #pragma unroll
        for (int nt = 0; nt < 4; ++nt)
          acc[mt][nt] = __builtin_amdgcn_mfma_f32_16x16x32_bf16(
              af[mt], bfr[nt], acc[mt][nt], 0, 0, 0);
    }

    if (k < 15) {
      __builtin_amdgcn_sched_barrier(0);
      __builtin_amdgcn_s_barrier();
      __builtin_amdgcn_sched_barrier(0);
    }
  }

  #pragma unroll
  for (int mt = 0; mt < 2; ++mt)
    #pragma unroll
    for (int r = 0; r < 4; ++r) {
      int row = row0 + wr + mt * 16 + quad * 4 + r;
      #pragma unroll
      for (int nt = 0; nt < 4; ++nt) {
        int col = col0 + wc + nt * 16 + col16;
        C[(size_t)row * D_ + col] = acc[mt][nt][r];
      }
    }
}

// ---------------------------------------------------------------------------
// Flash attention, 8-wave key-parity structure (unchanged from R2):
//   1 q-tile (64 rows) per block, 512 threads: wave w -> row-group rw = w&3,
//   key-parity p = w>>2 (halves g ≡ p mod 2). Fixed-max softmax -> parity
//   partials combine by pure addition. Rolling K/V slots, counted vmcnt(2).
// ---------------------------------------------------------------------------
__global__ __launch_bounds__(512, 6)
void attn_mfma(const unsigned short* __restrict__ Q,
               const unsigned short* __restrict__ K,
               const unsigned short* __restrict__ Vt,
               unsigned short* __restrict__ O)
{
  const int f   = blockIdx.x;          // 0..1023
  const int qt  = 31 - (f >> 5);       // big q-tiles dispatched first
  const int bh  = f & 31;              // xcd = f&7 ~ bh&7 -> L2 locality
  const int b   = bh >> 4, h = bh & 15;

  const int tid  = threadIdx.x;
  const int w    = tid >> 6;
  const int lane = tid & 63;
  const int quad = lane >> 4;
  const int col  = lane & 15;
  const int rw   = w & 3;              // row-wave 0..3
  const int p    = w >> 2;             // key-parity group 0/1
  const int qlocal = rw * 16 + col;

  __shared__ unsigned short Ks[2 * 4096];               // 2 x 64-key slot, 16 KB
  __shared__ unsigned short Vs[2 * 4096];               // 16 KB
  __shared__ __align__(16) unsigned short Pl[8][16][72]; // 18 KB, per-wave P

  const size_t qkbase = (size_t)b * S_ * D_ + (size_t)h * DK_;
  const size_t vtbase = (size_t)bh * DK_ * S_;

  const int qrow = qt * 64 + qlocal;
  bf16x8 qf[2];
  qf[0] = *(const bf16x8*)(Q + qkbase + (size_t)qrow * D_ + quad * 8);
  qf[1] = *(const bf16x8*)(Q + qkbase + (size_t)qrow * D_ + 32 + quad * 8);

  // staging: wave covers 16 rows (2 gloads x 8 rows) of its own slot p.
  const int lr8 = lane >> 3;                       // 0..7 row within 8
  const int sj  = ((lane & 7) ^ (lr8 & 7)) * 8;    // swizzled source octet

  auto stageK = [&](int g) {
    const int gc = (g > qt) ? qt : g;
    const unsigned short* s =
        K + qkbase + (size_t)(gc * 64 + rw * 16 + lr8) * D_ + sj;
    #pragma unroll
    for (int pp = 0; pp < 2; ++pp)
      gload_lds16(s + (size_t)(pp * 8) * D_, &Ks[p * 4096 + (rw * 16 + pp * 8) * 64]);
  };
  auto stageV = [&](int g) {
    const int gc = (g > qt) ? qt : g;
    const unsigned short* s =
        Vt + vtbase + (size_t)(rw * 16 + lr8) * S_ + gc * 64 + sj;
    #pragma unroll
    for (int pp = 0; pp < 2; ++pp)
      gload_lds16(s + (size_t)(pp * 8) * S_, &Vs[p * 4096 + (rw * 16 + pp * 8) * 64]);
  };

  f32x4 Oacc[4];
  #pragma unroll
  for (int nb = 0; nb < 4; ++nb)
    #pragma unroll
    for (int r = 0; r < 4; ++r) Oacc[nb][r] = 0.f;
  float l_i = 0.f;

  const int M  = (qt >> 1) + 1;        // pair-iterations
  const int jx = quad ^ (col & 7);
  const unsigned short* KsH = Ks + p * 4096;
  const unsigned short* VsH = Vs + p * 4096;
  unsigned short (*Plw)[72] = Pl[w];

  stageK(p);
  stageV(p);
  asm volatile("s_waitcnt vmcnt(0)" ::: "memory");
  __builtin_amdgcn_s_barrier();
  __builtin_amdgcn_sched_barrier(0);

  for (int m = 0; m < M; ++m) {
    const int g    = 2 * m + p;
    const bool act = (g <= qt);
    const bool dg  = (g == qt);

    f32x4 st[4];
    if (act) {                       // QK^T from own K slot
      __builtin_amdgcn_s_setprio(1);
      #pragma unroll
      for (int nb = 0; nb < 4; ++nb) {
        const int s0 = (nb * 16 + col) * 8 + jx;
        bf16x8 ka0 = *(const bf16x8*)(KsH + s0 * 8);
        bf16x8 ka1 = *(const bf16x8*)(KsH + (s0 ^ 4) * 8);
        f32x4 a = {-24.f, -24.f, -24.f, -24.f};   // fixed-max bias
        a = __builtin_amdgcn_mfma_f32_16x16x32_bf16(ka0, qf[0], a, 0, 0, 0);
        a = __builtin_amdgcn_mfma_f32_16x16x32_bf16(ka1, qf[1], a, 0, 0, 0);
        st[nb] = a;
      }
      __builtin_amdgcn_s_setprio(0);
    }
    __builtin_amdgcn_sched_barrier(0);
    __builtin_amdgcn_s_barrier();            // all QK K-reads complete
    __builtin_amdgcn_sched_barrier(0);

    stageK(2 * m + 2 + p);                   // overwrite own K slot (next pair)

    if (act) {                               // softmax (fixed-max, exp2 domain)
      if (dg) {
        #pragma unroll
        for (int nb = 0; nb < 4; ++nb)
          #pragma unroll
          for (int r = 0; r < 4; ++r)
            if (nb * 16 + quad * 4 + r > qlocal) st[nb][r] = -1e30f;
      }
      float rsum = 0.f;
      #pragma unroll
      for (int nb = 0; nb < 4; ++nb)
        #pragma unroll
        for (int r = 0; r < 4; ++r) {
          float pv = fast_exp2(st[nb][r]);
          st[nb][r] = pv;
          rsum += pv;
        }
      rsum += __shfl_xor(rsum, 16);
      rsum += __shfl_xor(rsum, 32);
      l_i += rsum;
      #pragma unroll
      for (int nb = 0; nb < 4; ++nb) {
        uint2 pk;
        pk.x = pack_trunc(st[nb][0], st[nb][1]);
        pk.y = pack_trunc(st[nb][2], st[nb][3]);
        *(uint2*)&Plw[col][nb * 16 + quad * 4] = pk;
      }
    }

    asm volatile("s_waitcnt vmcnt(2)" ::: "memory");  // own V(pair m) landed
    __builtin_amdgcn_sched_barrier(0);
    __builtin_amdgcn_s_barrier();            // everyone's V landed
    __builtin_amdgcn_sched_barrier(0);

    if (act) {                               // PV from own V slot
      bf16x8 pf0 = *(const bf16x8*)&Plw[col][quad * 8];
      bf16x8 pf1 = *(const bf16x8*)&Plw[col][32 + quad * 8];
      __builtin_amdgcn_s_setprio(1);
      #pragma unroll
      for (int nb = 0; nb < 4; ++nb) {
        const int s0 = (nb * 16 + col) * 8 + jx;
        bf16x8 va0 = *(const bf16x8*)(VsH + s0 * 8);
        bf16x8 va1 = *(const bf16x8*)(VsH + (s0 ^ 4) * 8);
        Oacc[nb] = __builtin_amdgcn_mfma_f32_16x16x32_bf16(va0, pf0, Oacc[nb], 0, 0, 0);
        Oacc[nb] = __builtin_amdgcn_mfma_f32_16x16x32_bf16(va1, pf1, Oacc[nb], 0, 0, 0);
      }
      __builtin_amdgcn_s_setprio(0);
    }
    __builtin_amdgcn_sched_barrier(0);
    __builtin_amdgcn_s_barrier();            // all V-reads complete
    __builtin_amdgcn_sched_barrier(0);

    stageV(2 * m + 2 + p);                   // overwrite own V slot (next pair)
    asm volatile("s_waitcnt vmcnt(2)" ::: "memory");  // own K(next) landed
    __builtin_amdgcn_sched_barrier(0);
    __builtin_amdgcn_s_barrier();            // everyone's K landed
    __builtin_amdgcn_sched_barrier(0);
  }

  // ---- combine parity partials (pure add: fixed-max, no rescale) ----
  asm volatile("s_waitcnt vmcnt(0)" ::: "memory");    // tail DMA landed
  __syncthreads();                                    // LDS reusable
  float* sc = (float*)&Pl[0][0][0];                   // 18 KB scratch
  if (p == 1) {
    float* d0 = sc + ((size_t)(rw * 64 + lane)) * 18;
    #pragma unroll
    for (int nb = 0; nb < 4; ++nb)
      #pragma unroll
      for (int r = 0; r < 4; ++r) d0[nb * 4 + r] = Oacc[nb][r];
    d0[16] = l_i;
  }
  __syncthreads();
  if (p == 0) {
    const float* s0 = sc + ((size_t)(rw * 64 + lane)) * 18;
    const float inv = 1.0f / (l_i + s0[16]);
    #pragma unroll
    for (int nb = 0; nb < 4; ++nb) {
      int d = nb * 16 + quad * 4;
      ushort4 oa;
      oa.x = f2bf((Oacc[nb][0] + s0[nb * 4 + 0]) * inv);
      oa.y = f2bf((Oacc[nb][1] + s0[nb * 4 + 1]) * inv);
      oa.z = f2bf((Oacc[nb][2] + s0[nb * 4 + 2]) * inv);
      oa.w = f2bf((Oacc[nb][3] + s0[nb * 4 + 3]) * inv);
      *(ushort4*)(O + (size_t)b * S_ * D_ + (size_t)qrow * D_ + h * DK_ + d) = oa;
    }
  }
}

// ---------------------------------------------------------------------------
extern "C" void kernel_launch(void* const* d_in, const int* in_sizes, int n_in,
                              void* d_out, int out_size, void* d_ws, size_t ws_size,
                              hipStream_t stream)
{
  const float* x  = (const float*)d_in[0];
  const float* Wq = (const float*)d_in[1];
  const float* Wk = (const float*)d_in[2];
  const float* Wv = (const float*)d_in[3];
  const float* Wo = (const float*)d_in[4];
  const int*   tp = (const int*)d_in[5];
  float* out = (float*)d_out;

  const size_t NTOK = (size_t)B_ * S_ * D_;     // 4,194,304 elements
  const size_t NW   = (size_t)D_ * D_;          // 1,048,576
  unsigned short* qh  = (unsigned short*)d_ws;  // bf16 [B,S,D]
  unsigned short* kh  = qh + NTOK;
  unsigned short* vt  = kh + NTOK;              // bf16 [B*H, 64, S]
  unsigned short* xb  = vt + NTOK;              // bf16 [B,S,D]; reused as ab
  unsigned short* wqb = xb + NTOK;
  unsigned short* wkb = wqb + NW;
  unsigned short* wvb = wkb + NW;
  unsigned short* wob = wvb + NW;
  unsigned short* ab  = xb;                     // alias: xb dead after QKV gemm

  // fp32 -> bf16 casts
  cast5_bf16<<<dim3(4096), 256, 0, stream>>>(
      x, Wq, Wk, Wv, Wo, xb, wqb, wkb, wvb, wob);

  // fused QKV projection + RoPE + Q-scale + direct-V^T (operand swap), BK=64
  gemm_qkv<<<dim3(D_ / 128, (B_ * S_) / 128, 3), 256, 0, stream>>>(
      xb, wqb, wkb, wvb, qh, kh, vt, tp);

  // 8-wave key-parity flash attention (fixed-max softmax) -> bf16 ab
  attn_mfma<<<dim3(32 * 32), 512, 0, stream>>>(qh, kh, vt, ab);

  // output projection, 64x128 tiles, BK=64 -> fp32 out
  gemm_wo<<<dim3(D_ / 128, (B_ * S_) / 64), 256, 0, stream>>>(ab, wob, out);
}

// Round 5
// 169.385 us; speedup vs baseline: 1.1164x; 1.0177x over previous
//
#include <hip/hip_runtime.h>
#include <hip/hip_bf16.h>
#include <math.h>

#define B_  2
#define S_  2048
#define H_  16
#define D_  1024
#define DK_ 64

typedef __attribute__((ext_vector_type(8))) short bf16x8;   // 8 bf16 = 4 VGPRs
typedef __attribute__((ext_vector_type(8))) unsigned short ushort8v;
typedef __attribute__((ext_vector_type(4))) float f32x4;

__device__ __forceinline__ unsigned short f2bf(float f) {
  unsigned u = __float_as_uint(f);
  unsigned r = (u + 0x7FFFu + ((u >> 16) & 1u)) >> 16;   // RNE
  return (unsigned short)r;
}
// truncation pack: two fp32 -> packed bf16x2 (P>=0; relative err ~2^-8, OK)
__device__ __forceinline__ unsigned pack_trunc(float lo, float hi) {
  return (__float_as_uint(lo) >> 16) | (__float_as_uint(hi) & 0xffff0000u);
}
__device__ __forceinline__ float fast_exp2(float x) {
#if __has_builtin(__builtin_amdgcn_exp2f)
  return __builtin_amdgcn_exp2f(x);
#else
  return __expf(x * 0.69314718056f);
#endif
}
// async global->LDS, 16B/lane. LDS dest = wave-uniform base + lane*16.
__device__ __forceinline__ void gload_lds16(const unsigned short* g,
                                            unsigned short* l) {
  __builtin_amdgcn_global_load_lds(
      (const __attribute__((address_space(1))) unsigned int*)(const void*)g,
      (__attribute__((address_space(3))) unsigned int*)(void*)l, 16, 0, 0);
}

// ---------------------------------------------------------------------------
// Cast fp32 -> bf16 for x (2048 blocks) + 4 weights (512 blocks each).
// ---------------------------------------------------------------------------
__global__ __launch_bounds__(256)
void cast5_bf16(const float* __restrict__ x,  const float* __restrict__ wq,
                const float* __restrict__ wk, const float* __restrict__ wv,
                const float* __restrict__ wo,
                unsigned short* __restrict__ xb,  unsigned short* __restrict__ wqb,
                unsigned short* __restrict__ wkb, unsigned short* __restrict__ wvb,
                unsigned short* __restrict__ wob)
{
  const int idx = blockIdx.x;
  const float* s; unsigned short* d; int lblk;
  if (idx < 2048) { s = x; d = xb; lblk = idx; }
  else {
    int t = idx - 2048;
    int w = t >> 9;          // 0..3
    lblk  = t & 511;
    s = (w == 0) ? wq  : (w == 1) ? wk  : (w == 2) ? wv  : wo;
    d = (w == 0) ? wqb : (w == 1) ? wkb : (w == 2) ? wvb : wob;
  }
  size_t i0 = ((size_t)lblk * 256 + threadIdx.x) * 8;
  float4 v0 = *(const float4*)(s + i0);
  float4 v1 = *(const float4*)(s + i0 + 4);
  ushort8v o;
  o[0] = f2bf(v0.x); o[1] = f2bf(v0.y); o[2] = f2bf(v0.z); o[3] = f2bf(v0.w);
  o[4] = f2bf(v1.x); o[5] = f2bf(v1.y); o[6] = f2bf(v1.z); o[7] = f2bf(v1.w);
  *(ushort8v*)(d + i0) = o;
}

// ---------------------------------------------------------------------------
// Fused QKV projection GEMM. R5: 64(M)x128(N) tiles -> 512 blocks per z
// (1536 total, ~6 queued/CU), 24 KB single-buffered LDS (R2-proven
// syncthreads staging; R4's dbuf+vmcnt was neutral). Mod-8 XOR swizzle rows.
// blockIdx.z: 0=Q, 1=K, 2=V (operand swap -> V^T).
// Per-z block decode keeps each XCD's panels contiguous (<=3MB, L2-fit).
// ---------------------------------------------------------------------------
__global__ __launch_bounds__(256)
void gemm_qkv(const unsigned short* __restrict__ A0,
              const unsigned short* __restrict__ W0,
              const unsigned short* __restrict__ W1,
              const unsigned short* __restrict__ W2,
              unsigned short* __restrict__ qh,
              unsigned short* __restrict__ kh,
              unsigned short* __restrict__ vt,
              const int* __restrict__ tp)
{
  const int z    = blockIdx.z;
  const int flat = blockIdx.y * 8 + blockIdx.x;   // 0..511
  const int xcd  = flat & 7;
  const int u    = flat >> 3;                     // 0..63

  int row0, col0;
  if (z < 2) {
    // token 64-row tiles: by = xcd*8+(u&7) in 0..63, bx = u>>3 in 0..7
    row0 = (xcd * 8 + (u & 7)) * 64;
    col0 = (u >> 3) * 128;
  } else {
    // channel 64-row tiles (cr 0..15) x token 128-col tiles (tc 0..31)
    int tc = xcd * 4 + (u & 3);
    int cr = u >> 2;
    row0 = cr * 64;
    col0 = tc * 128;
  }
  const unsigned short* Aptr = (z == 2) ? W2 : A0;
  const unsigned short* Bptr = (z == 0) ? W0 : (z == 1) ? W1 : A0;

  __shared__ unsigned short As[64 * 64];    // 8 KB
  __shared__ unsigned short Bs[128 * 64];   // 16 KB
  __shared__ int tps[64];

  const int tid   = threadIdx.x;
  const int wave  = tid >> 6;
  const int lane  = tid & 63;
  const int quad  = lane >> 4;
  const int col16 = lane & 15;
  const int wr    = (wave >> 1) * 32;
  const int wc    = (wave & 1) * 64;

  if (z < 2 && tid < 64) tps[tid] = tp[row0 + tid];

  const int srow = wave * 8 + (lane >> 3);
  const int scol = ((lane & 7) ^ ((lane >> 3) & 7)) * 8;
  const unsigned short* gA = Aptr + (size_t)(row0 + srow) * D_ + scol;
  const unsigned short* gB = Bptr + (size_t)(col0 + srow) * D_ + scol;

  f32x4 acc[2][4];
  #pragma unroll
  for (int mt = 0; mt < 2; ++mt)
    #pragma unroll
    for (int nt = 0; nt < 4; ++nt)
      #pragma unroll
      for (int r = 0; r < 4; ++r) acc[mt][nt][r] = 0.f;

  for (int k0 = 0; k0 < D_; k0 += 64) {
    __syncthreads();
    #pragma unroll
    for (int p = 0; p < 2; ++p)
      gload_lds16(gA + (size_t)(p * 32) * D_ + k0, &As[(p * 32 + wave * 8) * 64]);
    #pragma unroll
    for (int p = 0; p < 4; ++p)
      gload_lds16(gB + (size_t)(p * 32) * D_ + k0, &Bs[(p * 32 + wave * 8) * 64]);
    __syncthreads();

    #pragma unroll
    for (int h = 0; h < 2; ++h) {
      const int jo = ((h * 4 + quad) ^ (col16 & 7)) * 8;
      bf16x8 af[2], bfr[4];
      #pragma unroll
      for (int mt = 0; mt < 2; ++mt)
        af[mt] = *(const bf16x8*)&As[(wr + mt * 16 + col16) * 64 + jo];
      #pragma unroll
      for (int nt = 0; nt < 4; ++nt)
        bfr[nt] = *(const bf16x8*)&Bs[(wc + nt * 16 + col16) * 64 + jo];

      #pragma unroll
      for (int mt = 0; mt < 2; ++mt)
        #pragma unroll
        for (int nt = 0; nt < 4; ++nt)
          acc[mt][nt] = __builtin_amdgcn_mfma_f32_16x16x32_bf16(
              af[mt], bfr[nt], acc[mt][nt], 0, 0, 0);
    }
  }

  if (z == 2) {
    // C = V^T: row = channel c, col = token t; lanes are consecutive tokens.
    #pragma unroll
    for (int mt = 0; mt < 2; ++mt)
      #pragma unroll
      for (int r = 0; r < 4; ++r) {
        int c = row0 + wr + mt * 16 + quad * 4 + r;   // channel
        int h = c >> 6, d = c & 63;
        #pragma unroll
        for (int nt = 0; nt < 4; ++nt) {
          int t  = col0 + wc + nt * 16 + col16;       // token
          int bb = t >> 11, sl = t & (S_ - 1);
          vt[((size_t)((bb << 4) + h) * DK_ + d) * S_ + sl] =
              f2bf(acc[mt][nt][r]);
        }
      }
  } else {
    unsigned short* C = z ? kh : qh;
    const float qs = z ? 1.0f : 0.1803368801111204f;  // 0.125*log2(e) for Q
    const float sgn = (col16 & 1) ? 1.f : -1.f;       // even lane: re = v*c - o*s
    float freqr[4];
    #pragma unroll
    for (int nt = 0; nt < 4; ++nt) {
      int i = ((wc + nt * 16 + col16) & 63) >> 1;
      freqr[nt] = exp2f(-0.4152410118f * (float)i);   // 10000^(-2i/64)
    }
    #pragma unroll
    for (int mt = 0; mt < 2; ++mt)
      #pragma unroll
      for (int r = 0; r < 4; ++r) {
        int rl  = wr + mt * 16 + quad * 4 + r;
        int row = row0 + rl;
        float p = (float)tps[rl];
        #pragma unroll
        for (int nt = 0; nt < 4; ++nt) {
          int col = col0 + wc + nt * 16 + col16;
          float ang = p * freqr[nt];
          float sn = __sinf(ang), cs = __cosf(ang);
          float val = acc[mt][nt][r];
          float oth = __shfl_xor(val, 1);
          C[(size_t)row * D_ + col] = f2bf((val * cs + oth * sgn * sn) * qs);
        }
      }
  }
}

// ---------------------------------------------------------------------------
// Wo projection GEMM. R5: 64x64 tiles -> 1024 blocks (4/CU queued), 16 KB
// LDS, launch_bounds(256,8) to force VGPR<=64 -> 8 waves/SIMD residency.
// ---------------------------------------------------------------------------
__global__ __launch_bounds__(256, 8)
void gemm_wo(const unsigned short* __restrict__ A,
             const unsigned short* __restrict__ W,
             float* __restrict__ C)
{
  __shared__ unsigned short As[64 * 64];    // 8 KB
  __shared__ unsigned short Bs[64 * 64];    // 8 KB

  const int flat = blockIdx.y * 16 + blockIdx.x;  // 0..1023
  const int xcd  = flat & 7;
  const int u    = flat >> 3;                     // 0..127
  const int by   = xcd * 8 + (u & 7);             // 0..63
  const int bx   = u >> 3;                        // 0..15

  const int tid   = threadIdx.x;
  const int wave  = tid >> 6;
  const int lane  = tid & 63;
  const int quad  = lane >> 4;
  const int col16 = lane & 15;
  const int row0  = by * 64;
  const int col0  = bx * 64;
  const int wr    = (wave >> 1) * 32;
  const int wc    = (wave & 1) * 32;

  const int srow = wave * 8 + (lane >> 3);
  const int scol = ((lane & 7) ^ ((lane >> 3) & 7)) * 8;
  const unsigned short* gA = A + (size_t)(row0 + srow) * D_ + scol;
  const unsigned short* gB = W + (size_t)(col0 + srow) * D_ + scol;

  f32x4 acc[2][2];
  #pragma unroll
  for (int mt = 0; mt < 2; ++mt)
    #pragma unroll
    for (int nt = 0; nt < 2; ++nt)
      #pragma unroll
      for (int r = 0; r < 4; ++r) acc[mt][nt][r] = 0.f;

  for (int k0 = 0; k0 < D_; k0 += 64) {
    __syncthreads();
    #pragma unroll
    for (int p = 0; p < 2; ++p) {
      gload_lds16(gA + (size_t)(p * 32) * D_ + k0, &As[(p * 32 + wave * 8) * 64]);
      gload_lds16(gB + (size_t)(p * 32) * D_ + k0, &Bs[(p * 32 + wave * 8) * 64]);
    }
    __syncthreads();

    #pragma unroll
    for (int h = 0; h < 2; ++h) {
      const int jo = ((h * 4 + quad) ^ (col16 & 7)) * 8;
      bf16x8 af[2], bfr[2];
      #pragma unroll
      for (int mt = 0; mt < 2; ++mt)
        af[mt] = *(const bf16x8*)&As[(wr + mt * 16 + col16) * 64 + jo];
      #pragma unroll
      for (int nt = 0; nt < 2; ++nt)
        bfr[nt] = *(const bf16x8*)&Bs[(wc + nt * 16 + col16) * 64 + jo];

      #pragma unroll
      for (int mt = 0; mt < 2; ++mt)
        #pragma unroll
        for (int nt = 0; nt < 2; ++nt)
          acc[mt][nt] = __builtin_amdgcn_mfma_f32_16x16x32_bf16(
              af[mt], bfr[nt], acc[mt][nt], 0, 0, 0);
    }
  }

  #pragma unroll
  for (int mt = 0; mt < 2; ++mt)
    #pragma unroll
    for (int r = 0; r < 4; ++r) {
      int row = row0 + wr + mt * 16 + quad * 4 + r;
      #pragma unroll
      for (int nt = 0; nt < 2; ++nt) {
        int col = col0 + wc + nt * 16 + col16;
        C[(size_t)row * D_ + col] = acc[mt][nt][r];
      }
    }
}

// ---------------------------------------------------------------------------
// Flash attention, 8-wave key-parity structure (R2). R5: launch_bounds(512,8)
// forces VGPR<=64 (was 68 -> 128-quantum -> only 2 blocks/CU); now LDS-capped
// at 3 blocks/CU = 24 waves/CU (+50% residency).
// ---------------------------------------------------------------------------
__global__ __launch_bounds__(512, 8)
void attn_mfma(const unsigned short* __restrict__ Q,
               const unsigned short* __restrict__ K,
               const unsigned short* __restrict__ Vt,
               unsigned short* __restrict__ O)
{
  const int f   = blockIdx.x;          // 0..1023
  const int qt  = 31 - (f >> 5);       // big q-tiles dispatched first
  const int bh  = f & 31;              // xcd = f&7 ~ bh&7 -> L2 locality
  const int b   = bh >> 4, h = bh & 15;

  const int tid  = threadIdx.x;
  const int w    = tid >> 6;
  const int lane = tid & 63;
  const int quad = lane >> 4;
  const int col  = lane & 15;
  const int rw   = w & 3;              // row-wave 0..3
  const int p    = w >> 2;             // key-parity group 0/1
  const int qlocal = rw * 16 + col;

  __shared__ unsigned short Ks[2 * 4096];               // 2 x 64-key slot, 16 KB
  __shared__ unsigned short Vs[2 * 4096];               // 16 KB
  __shared__ __align__(16) unsigned short Pl[8][16][72]; // 18 KB, per-wave P

  const size_t qkbase = (size_t)b * S_ * D_ + (size_t)h * DK_;
  const size_t vtbase = (size_t)bh * DK_ * S_;

  const int qrow = qt * 64 + qlocal;
  bf16x8 qf[2];
  qf[0] = *(const bf16x8*)(Q + qkbase + (size_t)qrow * D_ + quad * 8);
  qf[1] = *(const bf16x8*)(Q + qkbase + (size_t)qrow * D_ + 32 + quad * 8);

  // staging: wave covers 16 rows (2 gloads x 8 rows) of its own slot p.
  const int lr8 = lane >> 3;                       // 0..7 row within 8
  const int sj  = ((lane & 7) ^ (lr8 & 7)) * 8;    // swizzled source octet

  auto stageK = [&](int g) {
    const int gc = (g > qt) ? qt : g;
    const unsigned short* s =
        K + qkbase + (size_t)(gc * 64 + rw * 16 + lr8) * D_ + sj;
    #pragma unroll
    for (int pp = 0; pp < 2; ++pp)
      gload_lds16(s + (size_t)(pp * 8) * D_, &Ks[p * 4096 + (rw * 16 + pp * 8) * 64]);
  };
  auto stageV = [&](int g) {
    const int gc = (g > qt) ? qt : g;
    const unsigned short* s =
        Vt + vtbase + (size_t)(rw * 16 + lr8) * S_ + gc * 64 + sj;
    #pragma unroll
    for (int pp = 0; pp < 2; ++pp)
      gload_lds16(s + (size_t)(pp * 8) * S_, &Vs[p * 4096 + (rw * 16 + pp * 8) * 64]);
  };

  f32x4 Oacc[4];
  #pragma unroll
  for (int nb = 0; nb < 4; ++nb)
    #pragma unroll
    for (int r = 0; r < 4; ++r) Oacc[nb][r] = 0.f;
  float l_i = 0.f;

  const int M  = (qt >> 1) + 1;        // pair-iterations
  const int jx = quad ^ (col & 7);
  const unsigned short* KsH = Ks + p * 4096;
  const unsigned short* VsH = Vs + p * 4096;
  unsigned short (*Plw)[72] = Pl[w];

  stageK(p);
  stageV(p);
  asm volatile("s_waitcnt vmcnt(0)" ::: "memory");
  __builtin_amdgcn_s_barrier();
  __builtin_amdgcn_sched_barrier(0);

  for (int m = 0; m < M; ++m) {
    const int g    = 2 * m + p;
    const bool act = (g <= qt);
    const bool dg  = (g == qt);

    f32x4 st[4];
    if (act) {                       // QK^T from own K slot
      __builtin_amdgcn_s_setprio(1);
      #pragma unroll
      for (int nb = 0; nb < 4; ++nb) {
        const int s0 = (nb * 16 + col) * 8 + jx;
        bf16x8 ka0 = *(const bf16x8*)(KsH + s0 * 8);
        bf16x8 ka1 = *(const bf16x8*)(KsH + (s0 ^ 4) * 8);
        f32x4 a = {-24.f, -24.f, -24.f, -24.f};   // fixed-max bias
        a = __builtin_amdgcn_mfma_f32_16x16x32_bf16(ka0, qf[0], a, 0, 0, 0);
        a = __builtin_amdgcn_mfma_f32_16x16x32_bf16(ka1, qf[1], a, 0, 0, 0);
        st[nb] = a;
      }
      __builtin_amdgcn_s_setprio(0);
    }
    __builtin_amdgcn_sched_barrier(0);
    __builtin_amdgcn_s_barrier();            // all QK K-reads complete
    __builtin_amdgcn_sched_barrier(0);

    stageK(2 * m + 2 + p);                   // overwrite own K slot (next pair)

    if (act) {                               // softmax (fixed-max, exp2 domain)
      if (dg) {
        #pragma unroll
        for (int nb = 0; nb < 4; ++nb)
          #pragma unroll
          for (int r = 0; r < 4; ++r)
            if (nb * 16 + quad * 4 + r > qlocal) st[nb][r] = -1e30f;
      }
      float rsum = 0.f;
      #pragma unroll
      for (int nb = 0; nb < 4; ++nb)
        #pragma unroll
        for (int r = 0; r < 4; ++r) {
          float pv = fast_exp2(st[nb][r]);
          st[nb][r] = pv;
          rsum += pv;
        }
      rsum += __shfl_xor(rsum, 16);
      rsum += __shfl_xor(rsum, 32);
      l_i += rsum;
      #pragma unroll
      for (int nb = 0; nb < 4; ++nb) {
        uint2 pk;
        pk.x = pack_trunc(st[nb][0], st[nb][1]);
        pk.y = pack_trunc(st[nb][2], st[nb][3]);
        *(uint2*)&Plw[col][nb * 16 + quad * 4] = pk;
      }
    }

    asm volatile("s_waitcnt vmcnt(2)" ::: "memory");  // own V(pair m) landed
    __builtin_amdgcn_sched_barrier(0);
    __builtin_amdgcn_s_barrier();            // everyone's V landed
    __builtin_amdgcn_sched_barrier(0);

    if (act) {                               // PV from own V slot
      bf16x8 pf0 = *(const bf16x8*)&Plw[col][quad * 8];
      bf16x8 pf1 = *(const bf16x8*)&Plw[col][32 + quad * 8];
      __builtin_amdgcn_s_setprio(1);
      #pragma unroll
      for (int nb = 0; nb < 4; ++nb) {
        const int s0 = (nb * 16 + col) * 8 + jx;
        bf16x8 va0 = *(const bf16x8*)(VsH + s0 * 8);
        bf16x8 va1 = *(const bf16x8*)(VsH + (s0 ^ 4) * 8);
        Oacc[nb] = __builtin_amdgcn_mfma_f32_16x16x32_bf16(va0, pf0, Oacc[nb], 0, 0, 0);
        Oacc[nb] = __builtin_amdgcn_mfma_f32_16x16x32_bf16(va1, pf1, Oacc[nb], 0, 0, 0);
      }
      __builtin_amdgcn_s_setprio(0);
    }
    __builtin_amdgcn_sched_barrier(0);
    __builtin_amdgcn_s_barrier();            // all V-reads complete
    __builtin_amdgcn_sched_barrier(0);

    stageV(2 * m + 2 + p);                   // overwrite own V slot (next pair)
    asm volatile("s_waitcnt vmcnt(2)" ::: "memory");  // own K(next) landed
    __builtin_amdgcn_sched_barrier(0);
    __builtin_amdgcn_s_barrier();            // everyone's K landed
    __builtin_amdgcn_sched_barrier(0);
  }

  // ---- combine parity partials (pure add: fixed-max, no rescale) ----
  asm volatile("s_waitcnt vmcnt(0)" ::: "memory");    // tail DMA landed
  __syncthreads();                                    // LDS reusable
  float* sc = (float*)&Pl[0][0][0];                   // 18 KB scratch
  if (p == 1) {
    float* d0 = sc + ((size_t)(rw * 64 + lane)) * 18;
    #pragma unroll
    for (int nb = 0; nb < 4; ++nb)
      #pragma unroll
      for (int r = 0; r < 4; ++r) d0[nb * 4 + r] = Oacc[nb][r];
    d0[16] = l_i;
  }
  __syncthreads();
  if (p == 0) {
    const float* s0 = sc + ((size_t)(rw * 64 + lane)) * 18;
    const float inv = 1.0f / (l_i + s0[16]);
    #pragma unroll
    for (int nb = 0; nb < 4; ++nb) {
      int d = nb * 16 + quad * 4;
      ushort4 oa;
      oa.x = f2bf((Oacc[nb][0] + s0[nb * 4 + 0]) * inv);
      oa.y = f2bf((Oacc[nb][1] + s0[nb * 4 + 1]) * inv);
      oa.z = f2bf((Oacc[nb][2] + s0[nb * 4 + 2]) * inv);
      oa.w = f2bf((Oacc[nb][3] + s0[nb * 4 + 3]) * inv);
      *(ushort4*)(O + (size_t)b * S_ * D_ + (size_t)qrow * D_ + h * DK_ + d) = oa;
    }
  }
}

// ---------------------------------------------------------------------------
extern "C" void kernel_launch(void* const* d_in, const int* in_sizes, int n_in,
                              void* d_out, int out_size, void* d_ws, size_t ws_size,
                              hipStream_t stream)
{
  const float* x  = (const float*)d_in[0];
  const float* Wq = (const float*)d_in[1];
  const float* Wk = (const float*)d_in[2];
  const float* Wv = (const float*)d_in[3];
  const float* Wo = (const float*)d_in[4];
  const int*   tp = (const int*)d_in[5];
  float* out = (float*)d_out;

  const size_t NTOK = (size_t)B_ * S_ * D_;     // 4,194,304 elements
  const size_t NW   = (size_t)D_ * D_;          // 1,048,576
  unsigned short* qh  = (unsigned short*)d_ws;  // bf16 [B,S,D]
  unsigned short* kh  = qh + NTOK;
  unsigned short* vt  = kh + NTOK;              // bf16 [B*H, 64, S]
  unsigned short* xb  = vt + NTOK;              // bf16 [B,S,D]; reused as ab
  unsigned short* wqb = xb + NTOK;
  unsigned short* wkb = wqb + NW;
  unsigned short* wvb = wkb + NW;
  unsigned short* wob = wvb + NW;
  unsigned short* ab  = xb;                     // alias: xb dead after QKV gemm

  // fp32 -> bf16 casts
  cast5_bf16<<<dim3(4096), 256, 0, stream>>>(
      x, Wq, Wk, Wv, Wo, xb, wqb, wkb, wvb, wob);

  // fused QKV projection + RoPE + Q-scale + direct-V^T, 64x128 tiles
  gemm_qkv<<<dim3(8, 64, 3), 256, 0, stream>>>(
      xb, wqb, wkb, wvb, qh, kh, vt, tp);

  // 8-wave key-parity flash attention (fixed-max softmax) -> bf16 ab
  attn_mfma<<<dim3(32 * 32), 512, 0, stream>>>(qh, kh, vt, ab);

  // output projection, 64x64 tiles -> fp32 out
  gemm_wo<<<dim3(16, 64), 256, 0, stream>>>(ab, wob, out);
}